// Round 8
// baseline (407.910 us; speedup 1.0000x reference)
//
#include <hip/hip_runtime.h>
#include <hip/hip_bf16.h>

// GraphSAGE-LSTM aggregator, MI355X (gfx950).  B=16384, T=25, D=128, U=128.
// R8 changes vs R7 (R7: 178us lstm, stall-bound: 2 barriers/step with full
// vmcnt drains + lockstep MFMA/gates phases; MFMA floor is 52us):
//  - x LDS tile ELIMINATED: x@W A-fragments gathered per-wave directly from
//    global (16B/lane at feats[ni*128 + kt*32 + lhi*8]); L2 dedups the 8x
//    wave overlap. Frees LDS for double-buffered h.
//  - ONE barrier per step (was 2): MFMA->gates is wave-private (no sync);
//    h written to hb[p^1] while hb[p] is read; epilogue needs no barrier.
//  - phase order per step: issue x+W+idx loads (sched_barrier pinned) ->
//    h@U (LDS-fed, hides global latency) -> x@W -> gates -> h-write -> bar.
//  - prep kernels merged into one launch.
// LDS: ub 128K (U frags) + hb 2x16K = 160 KiB exactly.  1 block/CU.
// ws layout (bf16 elems):
//   [0, 147456)            weight fragments (W, U, node_weights)
//   [262144, 13062144)     features as bf16 (100000 x 128)
// ws_size needed: 26.2 MB.

typedef __bf16 bf16;
typedef __bf16 bf16x8 __attribute__((ext_vector_type(8)));
typedef float f32x4 __attribute__((ext_vector_type(4)));

#define FEATS_OFF 262144

__device__ __forceinline__ float fast_sig(float x) {
  float e = __builtin_amdgcn_exp2f(-1.442695041f * x);
  return __builtin_amdgcn_rcpf(1.0f + e);
}
__device__ __forceinline__ float fast_tanh(float x) {
  float e = __builtin_amdgcn_exp2f(-2.885390082f * x);
  return (1.0f - e) * __builtin_amdgcn_rcpf(1.0f + e);
}
__device__ __forceinline__ f32x4 splat4(float x) {
  f32x4 v; v[0] = x; v[1] = x; v[2] = x; v[3] = x; return v;
}
__device__ __forceinline__ bf16x8 pack8(float4 a, float4 b) {
  bf16x8 v;
  v[0] = (bf16)a.x; v[1] = (bf16)a.y; v[2] = (bf16)a.z; v[3] = (bf16)a.w;
  v[4] = (bf16)b.x; v[5] = (bf16)b.y; v[6] = (bf16)b.z; v[7] = (bf16)b.w;
  return v;
}

// ---------------- prep: weights frag-pack + feature bf16 convert ----------------
// Fragment semantics (B operand of 16x16x32): lane supplies
//   B[k = kt*32 + (lane>>4)*8 + j][col], col = g*128 + ug*16 + (lane&15).
__global__ void prep_all(const float* __restrict__ W, const float* __restrict__ U,
                         const float* __restrict__ NW, const float4* __restrict__ feats,
                         bf16* __restrict__ ws) {
  int gid = blockIdx.x * 256 + threadIdx.x;
  if (gid < 147456) {
    int idx = gid;
    if (idx < 131072) {
      const float* __restrict__ src = (idx < 65536) ? W : U;
      int r = idx & 65535;
      int f = r >> 9, lane = (r >> 3) & 63, j = r & 7;
      int kt = f & 3, g = (f >> 2) & 3, w = f >> 4;
      int k = kt * 32 + (lane >> 4) * 8 + j;
      int col = g * 128 + w * 16 + (lane & 15);
      ws[idx] = (bf16)src[k * 512 + col];
    } else {
      int r = idx - 131072;
      int f = r >> 9, lane = (r >> 3) & 63, j = r & 7;
      int kt = f & 3, w = f >> 2;
      int k = kt * 32 + (lane >> 4) * 8 + j;
      int col = w * 16 + (lane & 15);
      ws[idx] = (bf16)NW[k * 128 + col];
    }
  }
  bf16x8* __restrict__ fo = (bf16x8*)(ws + FEATS_OFF);
  int stride = gridDim.x * 256;
  for (int i = gid; i < 1600000; i += stride) {  // 100000*128/8
    float4 a = feats[2 * i], b = feats[2 * i + 1];
    __builtin_nontemporal_store(pack8(a, b), fo + i);
  }
}

// ---------------- fused LSTM aggregator ----------------
__global__ __launch_bounds__(512, 2)
void lstm_kernel(const int* __restrict__ node, const int* __restrict__ neigh,
                 const float* __restrict__ bias, const bf16* __restrict__ wsf,
                 float* __restrict__ out) {
  __shared__ char ub[131072];  // U fragments, frag-linear (copied from ws)
  __shared__ char hb[32768];   // h tile, 2 x [64 rows][128] bf16, XOR-swizzled

  const int tid  = threadIdx.x;
  const int lane = tid & 63;
  const int ug   = tid >> 6;       // wave = unit group: units [ug*16, ug*16+16)
  const int l15  = lane & 15;
  const int lhi  = lane >> 4;
  const int b0   = blockIdx.x * 64;
  const bf16* __restrict__ fb = wsf + FEATS_OFF;

  // ---- prologue: fill U-frag LDS (straight 128 KB copy, once per block) ----
#pragma unroll
  for (int i = 0; i < 16; ++i) {
    int k = i * 512 + tid;  // 8192 chunks of 16 B
    ((bf16x8*)ub)[k] = *(const bf16x8*)(wsf + 65536 + k * 8);
  }

  float bb[4];
#pragma unroll
  for (int g = 0; g < 4; ++g) bb[g] = bias[g * 128 + ug * 16 + l15];

  f32x4 cc[4];  // cell state: row = m*16 + lhi*4 + r, unit = ug*16 + l15
#pragma unroll
  for (int m = 0; m < 4; ++m) cc[m] = splat4(0.0f);

  // Per-lane neighbour index for each M-tile's row (row = b0 + m*16 + l15).
  int niv[4];
#pragma unroll
  for (int m = 0; m < 4; ++m) niv[m] = neigh[(b0 + m * 16 + l15) * 25];

  __syncthreads();  // ub ready

  f32x4 acc[4][4];                 // [gate][Mtile]
  const int asw = (l15 & 7) << 4;  // A-frag row swizzle (row&7 == l15&7)

  float hl[4][4];                  // final h (written by gates at t=24)

#pragma unroll 1
  for (int t = 0; t < 25; ++t) {
    const int pcur = t & 1;
    const char* hrd = hb + pcur * 16384;
    char*       hwr = hb + (pcur ^ 1) * 16384;

    // 1. x A-fragments gathered directly from global (oldest in vmem queue)
    bf16x8 xa[4][4];
#pragma unroll
    for (int m = 0; m < 4; ++m) {
      const bf16* bp = fb + (size_t)niv[m] * 128 + lhi * 8;
#pragma unroll
      for (int kt = 0; kt < 4; ++kt)
        xa[m][kt] = __builtin_nontemporal_load((const bf16x8*)(bp + kt * 32));
    }
    // 2. W fragment loads (L2-resident)
    bf16x8 wf[4][4];
#pragma unroll
    for (int g = 0; g < 4; ++g)
#pragma unroll
      for (int kt = 0; kt < 4; ++kt)
        wf[g][kt] = *(const bf16x8*)(wsf + (((ug * 4 + g) * 4 + kt) << 9) + (lane << 3));
    // 3. next-step index prefetch
    if (t < 24) {
#pragma unroll
      for (int m = 0; m < 4; ++m)
        niv[m] = (t < 24 - 1) ? neigh[(b0 + m * 16 + l15) * 25 + t + 1]
                              : neigh[(b0 + m * 16 + l15) * 25 + 24];
    } else {
#pragma unroll
      for (int m = 0; m < 4; ++m) niv[m] = node[b0 + m * 16 + l15];
    }
    __builtin_amdgcn_sched_barrier(0);  // pin: all loads issued before MFMAs

    // 4. acc init
#pragma unroll
    for (int g = 0; g < 4; ++g) {
      f32x4 bi = splat4(bb[g]);
#pragma unroll
      for (int m = 0; m < 4; ++m) acc[g][m] = bi;
    }

    // 5. h@U first (pure LDS-fed; hides the global-load latency of xa/wf)
    if (t > 0) {
#pragma unroll
      for (int kt = 0; kt < 4; ++kt) {
        bf16x8 ufr[4];
#pragma unroll
        for (int g = 0; g < 4; ++g)
          ufr[g] = *(const bf16x8*)(ub + (((ug * 16 + g * 4 + kt) << 6 | lane) << 4));
        bf16x8 ha[4];
#pragma unroll
        for (int m = 0; m < 4; ++m)
          ha[m] = *(const bf16x8*)(hrd + (((m * 16 + l15) * 256 + (kt * 4 + lhi) * 16) ^ asw));
#pragma unroll
        for (int g = 0; g < 4; ++g)
#pragma unroll
          for (int m = 0; m < 4; ++m)
            acc[g][m] = __builtin_amdgcn_mfma_f32_16x16x32_bf16(ha[m], ufr[g], acc[g][m], 0, 0, 0);
      }
    }

    // 6. x@W
#pragma unroll
    for (int kt = 0; kt < 4; ++kt)
#pragma unroll
      for (int g = 0; g < 4; ++g)
#pragma unroll
        for (int m = 0; m < 4; ++m)
          acc[g][m] = __builtin_amdgcn_mfma_f32_16x16x32_bf16(xa[m][kt], wf[g][kt], acc[g][m], 0, 0, 0);

    // 7. gates (wave-private; no barrier needed after MFMAs)
    if (t < 24) {
#pragma unroll
      for (int m = 0; m < 4; ++m)
#pragma unroll
        for (int r = 0; r < 4; ++r) {
          float iv = fast_sig(acc[0][m][r]);
          float fv = fast_sig(acc[1][m][r]);
          float gv = fast_tanh(acc[2][m][r]);
          float ov = fast_sig(acc[3][m][r]);
          float cv = fv * cc[m][r] + iv * gv;
          cc[m][r] = cv;
          float hv = ov * fast_tanh(cv);
          int row = m * 16 + lhi * 4 + r;
          *(bf16*)(hwr + ((row * 256 + (ug * 16 + l15) * 2) ^ ((row & 7) << 4))) = (bf16)hv;
        }
      __syncthreads();  // h(t) visible for step t+1 (single barrier per step)
    } else {
#pragma unroll
      for (int m = 0; m < 4; ++m)
#pragma unroll
        for (int r = 0; r < 4; ++r) {
          float iv = fast_sig(acc[0][m][r]);
          float fv = fast_sig(acc[1][m][r]);
          float gv = fast_tanh(acc[2][m][r]);
          float ov = fast_sig(acc[3][m][r]);
          float cv = fv * cc[m][r] + iv * gv;
          hl[m][r] = ov * fast_tanh(cv);
        }
    }
  }

  // ----- from_self = node_feat @ node_weights; out = relu((s + h)/2) -----
  // niv now holds node[] indices (prefetched in t=24). No barrier needed.
  {
    bf16x8 xa[4][4];
#pragma unroll
    for (int m = 0; m < 4; ++m) {
      const bf16* bp = fb + (size_t)niv[m] * 128 + lhi * 8;
#pragma unroll
      for (int kt = 0; kt < 4; ++kt)
        xa[m][kt] = __builtin_nontemporal_load((const bf16x8*)(bp + kt * 32));
    }
    f32x4 accs[4];
#pragma unroll
    for (int m = 0; m < 4; ++m) accs[m] = splat4(0.0f);
#pragma unroll
    for (int kt = 0; kt < 4; ++kt) {
      bf16x8 nwf = *(const bf16x8*)(wsf + 131072 + ((ug * 4 + kt) << 9) + (lane << 3));
#pragma unroll
      for (int m = 0; m < 4; ++m)
        accs[m] = __builtin_amdgcn_mfma_f32_16x16x32_bf16(xa[m][kt], nwf, accs[m], 0, 0, 0);
    }
#pragma unroll
    for (int m = 0; m < 4; ++m)
#pragma unroll
      for (int r = 0; r < 4; ++r) {
        int row = m * 16 + lhi * 4 + r;
        float v = (accs[m][r] + hl[m][r]) * 0.5f;
        __builtin_nontemporal_store(v > 0.0f ? v : 0.0f,
                                    out + (b0 + row) * 128 + ug * 16 + l15);
      }
  }
}

extern "C" void kernel_launch(void* const* d_in, const int* in_sizes, int n_in,
                              void* d_out, int out_size, void* d_ws, size_t ws_size,
                              hipStream_t stream) {
  const float* feats = (const float*)d_in[0];   // 100000 x 128
  const int*   node  = (const int*)d_in[1];     // 16384 x 1
  const int*   neigh = (const int*)d_in[2];     // 16384 x 25
  const float* nw    = (const float*)d_in[3];   // 128 x 128
  const float* W     = (const float*)d_in[4];   // 128 x 512
  const float* U     = (const float*)d_in[5];   // 128 x 512
  const float* b     = (const float*)d_in[6];   // 512
  bf16* ws = (bf16*)d_ws;                       // needs 26.2 MB
  float* out = (float*)d_out;                   // 16384 x 128

  prep_all<<<2048, 256, 0, stream>>>(W, U, nw, (const float4*)feats, ws);
  lstm_kernel<<<256, 512, 0, stream>>>(node, neigh, b, ws, out);
}